// Round 1
// baseline (746.304 us; speedup 1.0000x reference)
//
#include <hip/hip_runtime.h>

// ---------------------------------------------------------------------------
// SpectralEncoder: ChebConv(K=4) x2 + mu/logvar heads.
// N=50000, E=600000, IN+PE = H = 128, L = 64, K = 4.
// Pipeline per call:
//   1. deg/cnt (atomics), dis = rsqrt(deg)
//   2. dst-CSR build: scan(cnt) -> row_ptr, scatter edges (src, w_norm)
//   3. h = concat(x, lap_pe)
//   4. per layer: T1..T3 via wave-per-node gather-prop, one K=512 GEMM
//   5. fused mu/logvar head GEMM -> d_out
// ---------------------------------------------------------------------------

__global__ void k_deg_cnt(const int* __restrict__ src, const int* __restrict__ dst,
                          const float* __restrict__ ew, float* __restrict__ deg,
                          int* __restrict__ cnt, int E) {
    int e = blockIdx.x * blockDim.x + threadIdx.x;
    if (e >= E) return;
    atomicAdd(&deg[src[e]], ew[e]);
    atomicAdd(&cnt[dst[e]], 1);
}

__global__ void k_dis(const float* __restrict__ deg, float* __restrict__ dis, int N) {
    int i = blockIdx.x * blockDim.x + threadIdx.x;
    if (i >= N) return;
    float d = deg[i];
    dis[i] = d > 0.f ? rsqrtf(fmaxf(d, 1e-12f)) : 0.f;
}

// single-block scan over cnt[0..N) -> exclusive prefix in row_ptr, copy to cursor
__global__ void k_scan(const int* __restrict__ cnt, int* __restrict__ row_ptr,
                       int* __restrict__ cursor, int N) {
    __shared__ int sdata[1024];
    __shared__ int carry;
    int tid = threadIdx.x;
    if (tid == 0) carry = 0;
    __syncthreads();
    for (int base = 0; base < N; base += 1024) {
        int i = base + tid;
        int v = (i < N) ? cnt[i] : 0;
        sdata[tid] = v;
        __syncthreads();
        #pragma unroll
        for (int off = 1; off < 1024; off <<= 1) {
            int t = (tid >= off) ? sdata[tid - off] : 0;
            __syncthreads();
            sdata[tid] += t;
            __syncthreads();
        }
        int excl = carry + sdata[tid] - v;
        if (i < N) { row_ptr[i] = excl; cursor[i] = excl; }
        __syncthreads();
        if (tid == 1023) carry += sdata[1023];
        __syncthreads();
    }
    if (tid == 0) row_ptr[N] = carry;
}

__global__ void k_scatter(const int* __restrict__ src, const int* __restrict__ dst,
                          const float* __restrict__ ew, const float* __restrict__ dis,
                          int* __restrict__ cursor, int* __restrict__ csr_src,
                          float* __restrict__ csr_w, int E) {
    int e = blockIdx.x * blockDim.x + threadIdx.x;
    if (e >= E) return;
    int s = src[e], d = dst[e];
    float wv = -dis[s] * ew[e] * dis[d];
    int pos = atomicAdd(&cursor[d], 1);
    csr_src[pos] = s;
    csr_w[pos] = wv;
}

__global__ void k_concat(const float* __restrict__ x, const float* __restrict__ pe,
                         float* __restrict__ h, int N) {
    int i = blockIdx.x * blockDim.x + threadIdx.x;
    if (i >= N * 128) return;
    int node = i >> 7, f = i & 127;
    h[i] = (f < 112) ? x[node * 112 + f] : pe[node * 16 + (f - 112)];
}

// out = scale * prop(tin) - (HAS_SUB ? sub : 0); one wave (64 lanes) per node,
// lane handles 2 consecutive feats (float2, 512B coalesced row gathers).
template<bool HAS_SUB>
__global__ void k_prop(const float* __restrict__ tin, const float* __restrict__ sub,
                       float scale, const int* __restrict__ row_ptr,
                       const int* __restrict__ csr_src, const float* __restrict__ csr_w,
                       float* __restrict__ out, int N) {
    int wid = (blockIdx.x * blockDim.x + threadIdx.x) >> 6;
    int lane = threadIdx.x & 63;
    if (wid >= N) return;
    int beg = row_ptr[wid], end = row_ptr[wid + 1];
    float ax = 0.f, ay = 0.f;
    int e = beg;
    for (; e + 1 < end; e += 2) {   // unroll x2 for load overlap
        int s0 = csr_src[e], s1 = csr_src[e + 1];
        float w0 = csr_w[e], w1 = csr_w[e + 1];
        float2 v0 = *(const float2*)&tin[(size_t)s0 * 128 + lane * 2];
        float2 v1 = *(const float2*)&tin[(size_t)s1 * 128 + lane * 2];
        ax = fmaf(w0, v0.x, ax); ay = fmaf(w0, v0.y, ay);
        ax = fmaf(w1, v1.x, ax); ay = fmaf(w1, v1.y, ay);
    }
    if (e < end) {
        int s0 = csr_src[e];
        float w0 = csr_w[e];
        float2 v0 = *(const float2*)&tin[(size_t)s0 * 128 + lane * 2];
        ax = fmaf(w0, v0.x, ax); ay = fmaf(w0, v0.y, ay);
    }
    float ox = scale * ax, oy = scale * ay;
    if (HAS_SUB) {
        float2 sv = *(const float2*)&sub[(size_t)wid * 128 + lane * 2];
        ox -= sv.x; oy -= sv.y;
    }
    *(float2*)&out[(size_t)wid * 128 + lane * 2] = make_float2(ox, oy);
}

// C[N,128] = relu?( sum_k A_k[N,128] @ W[k*128.. ,128] + bias ), K_total = 512.
// BM=64 rows/block, 256 threads, each thread 8 rows x 4 cols.
template<bool RELU>
__launch_bounds__(256)
__global__ void k_gemm512(const float* __restrict__ a0, const float* __restrict__ a1,
                          const float* __restrict__ a2, const float* __restrict__ a3,
                          const float* __restrict__ W, const float* __restrict__ bias,
                          float* __restrict__ C, int N) {
    __shared__ float lds_a[32][64];
    __shared__ float lds_w[32][128];
    const int tid = threadIdx.x;
    const int brow = blockIdx.x * 64;
    const int col = (tid & 31) * 4;
    const int rg = (tid >> 5) * 8;
    const int ar = tid & 63;
    const int akq = tid >> 6;
    const float* ap[4] = {a0, a1, a2, a3};
    float acc[8][4] = {};
    for (int kc = 0; kc < 512; kc += 32) {
        const float* A = ap[kc >> 7];
        const int kb = kc & 127;
        __syncthreads();
        {   // stage A chunk transposed: lds_a[k][row]
            int grow = brow + ar;
            #pragma unroll
            for (int j = 0; j < 2; ++j) {
                int k0 = akq * 8 + j * 4;
                float4 v = make_float4(0.f, 0.f, 0.f, 0.f);
                if (grow < N) v = *(const float4*)&A[(size_t)grow * 128 + kb + k0];
                lds_a[k0 + 0][ar] = v.x; lds_a[k0 + 1][ar] = v.y;
                lds_a[k0 + 2][ar] = v.z; lds_a[k0 + 3][ar] = v.w;
            }
            // stage W chunk rows kc..kc+31
            int wr = tid >> 3;
            int wc = (tid & 7) * 16;
            #pragma unroll
            for (int j = 0; j < 4; ++j) {
                *(float4*)&lds_w[wr][wc + j * 4] =
                    *(const float4*)&W[(size_t)(kc + wr) * 128 + wc + j * 4];
            }
        }
        __syncthreads();
        #pragma unroll 8
        for (int kk = 0; kk < 32; ++kk) {
            float4 w4 = *(const float4*)&lds_w[kk][col];
            float4 aA = *(const float4*)&lds_a[kk][rg];
            float4 aB = *(const float4*)&lds_a[kk][rg + 4];
            float a8[8] = {aA.x, aA.y, aA.z, aA.w, aB.x, aB.y, aB.z, aB.w};
            #pragma unroll
            for (int r = 0; r < 8; ++r) {
                acc[r][0] = fmaf(a8[r], w4.x, acc[r][0]);
                acc[r][1] = fmaf(a8[r], w4.y, acc[r][1]);
                acc[r][2] = fmaf(a8[r], w4.z, acc[r][2]);
                acc[r][3] = fmaf(a8[r], w4.w, acc[r][3]);
            }
        }
    }
    float4 b4 = *(const float4*)&bias[col];
    #pragma unroll
    for (int r = 0; r < 8; ++r) {
        int grow = brow + rg + r;
        if (grow < N) {
            float4 o = make_float4(acc[r][0] + b4.x, acc[r][1] + b4.y,
                                   acc[r][2] + b4.z, acc[r][3] + b4.w);
            if (RELU) {
                o.x = fmaxf(o.x, 0.f); o.y = fmaxf(o.y, 0.f);
                o.z = fmaxf(o.z, 0.f); o.w = fmaxf(o.w, 0.f);
            }
            *(float4*)&C[(size_t)grow * 128 + col] = o;
        }
    }
}

// fused heads: mu = A@Wm + bm ; lv = A@Wl + bl. A[N,128], W[128,64].
// BM=64 rows/block, 256 threads, each thread 4 rows x 4 cols x 2 heads.
__launch_bounds__(256)
__global__ void k_head(const float* __restrict__ A, const float* __restrict__ Wm,
                       const float* __restrict__ bm, const float* __restrict__ Wl,
                       const float* __restrict__ bl, float* __restrict__ out, int N) {
    __shared__ float lds_a[32][64];
    __shared__ float lds_wm[32][64];
    __shared__ float lds_wl[32][64];
    const int tid = threadIdx.x;
    const int brow = blockIdx.x * 64;
    const int col = (tid & 15) * 4;
    const int rg = (tid >> 4) * 4;
    const int ar = tid & 63;
    const int akq = tid >> 6;
    float am[4][4] = {}, al[4][4] = {};
    for (int kc = 0; kc < 128; kc += 32) {
        __syncthreads();
        {
            int grow = brow + ar;
            #pragma unroll
            for (int j = 0; j < 2; ++j) {
                int k0 = akq * 8 + j * 4;
                float4 v = make_float4(0.f, 0.f, 0.f, 0.f);
                if (grow < N) v = *(const float4*)&A[(size_t)grow * 128 + kc + k0];
                lds_a[k0 + 0][ar] = v.x; lds_a[k0 + 1][ar] = v.y;
                lds_a[k0 + 2][ar] = v.z; lds_a[k0 + 3][ar] = v.w;
            }
            int wr = tid >> 3;
            int wc = (tid & 7) * 8;
            #pragma unroll
            for (int j = 0; j < 2; ++j) {
                *(float4*)&lds_wm[wr][wc + j * 4] =
                    *(const float4*)&Wm[(size_t)(kc + wr) * 64 + wc + j * 4];
                *(float4*)&lds_wl[wr][wc + j * 4] =
                    *(const float4*)&Wl[(size_t)(kc + wr) * 64 + wc + j * 4];
            }
        }
        __syncthreads();
        #pragma unroll 8
        for (int kk = 0; kk < 32; ++kk) {
            float4 a4 = *(const float4*)&lds_a[kk][rg];
            float4 m4 = *(const float4*)&lds_wm[kk][col];
            float4 l4 = *(const float4*)&lds_wl[kk][col];
            float aa[4] = {a4.x, a4.y, a4.z, a4.w};
            #pragma unroll
            for (int r = 0; r < 4; ++r) {
                am[r][0] = fmaf(aa[r], m4.x, am[r][0]);
                am[r][1] = fmaf(aa[r], m4.y, am[r][1]);
                am[r][2] = fmaf(aa[r], m4.z, am[r][2]);
                am[r][3] = fmaf(aa[r], m4.w, am[r][3]);
                al[r][0] = fmaf(aa[r], l4.x, al[r][0]);
                al[r][1] = fmaf(aa[r], l4.y, al[r][1]);
                al[r][2] = fmaf(aa[r], l4.z, al[r][2]);
                al[r][3] = fmaf(aa[r], l4.w, al[r][3]);
            }
        }
    }
    float4 bm4 = *(const float4*)&bm[col];
    float4 bl4 = *(const float4*)&bl[col];
    #pragma unroll
    for (int r = 0; r < 4; ++r) {
        int grow = brow + rg + r;
        if (grow < N) {
            float4 om = make_float4(am[r][0] + bm4.x, am[r][1] + bm4.y,
                                    am[r][2] + bm4.z, am[r][3] + bm4.w);
            float4 ol = make_float4(al[r][0] + bl4.x, al[r][1] + bl4.y,
                                    al[r][2] + bl4.z, al[r][3] + bl4.w);
            *(float4*)&out[(size_t)grow * 64 + col] = om;
            *(float4*)&out[(size_t)N * 64 + (size_t)grow * 64 + col] = ol;
        }
    }
}

extern "C" void kernel_launch(void* const* d_in, const int* in_sizes, int n_in,
                              void* d_out, int out_size, void* d_ws, size_t ws_size,
                              hipStream_t stream) {
    const float* x   = (const float*)d_in[0];
    const int*   ei  = (const int*)d_in[1];
    const float* pe  = (const float*)d_in[2];
    const float* ew  = (const float*)d_in[3];
    const float* W1  = (const float*)d_in[4];
    const float* b1  = (const float*)d_in[5];
    const float* W2  = (const float*)d_in[6];
    const float* b2  = (const float*)d_in[7];
    const float* Wmu = (const float*)d_in[8];
    const float* bmu = (const float*)d_in[9];
    const float* Wlv = (const float*)d_in[10];
    const float* blv = (const float*)d_in[11];

    const int N = in_sizes[0] / 112;
    const int E = in_sizes[1] / 2;
    const int* src = ei;
    const int* dst = ei + E;

    char* ws = (char*)d_ws;
    size_t off = 0;
    auto alloc = [&](size_t bytes) -> char* {
        char* p = ws + off;
        off = (off + bytes + 255) & ~(size_t)255;
        return p;
    };
    float* deg     = (float*)alloc((size_t)N * 4);
    int*   cnt     = (int*)  alloc((size_t)N * 4);
    float* dis     = (float*)alloc((size_t)N * 4);
    int*   row_ptr = (int*)  alloc((size_t)(N + 1) * 4);
    int*   cursor  = (int*)  alloc((size_t)N * 4);
    int*   csr_src = (int*)  alloc((size_t)E * 4);
    float* csr_w   = (float*)alloc((size_t)E * 4);
    float* B0 = (float*)alloc((size_t)N * 128 * 4);
    float* B1 = (float*)alloc((size_t)N * 128 * 4);
    float* B2 = (float*)alloc((size_t)N * 128 * 4);
    float* B3 = (float*)alloc((size_t)N * 128 * 4);
    float* B4 = (float*)alloc((size_t)N * 128 * 4);

    hipMemsetAsync(deg, 0, (size_t)N * 4, stream);
    hipMemsetAsync(cnt, 0, (size_t)N * 4, stream);

    const int eb = (E + 255) / 256;
    const int nb = (N + 255) / 256;
    const int pb = (N + 3) / 4;     // wave-per-node, 4 waves/block
    const int gb = (N + 63) / 64;

    k_deg_cnt<<<eb, 256, 0, stream>>>(src, dst, ew, deg, cnt, E);
    k_dis<<<nb, 256, 0, stream>>>(deg, dis, N);
    k_scan<<<1, 1024, 0, stream>>>(cnt, row_ptr, cursor, N);
    k_scatter<<<eb, 256, 0, stream>>>(src, dst, ew, dis, cursor, csr_src, csr_w, E);
    k_concat<<<(N * 128 + 255) / 256, 256, 0, stream>>>(x, pe, B0, N);

    // layer 1: T0=B0, T1=B1, T2=B2, T3=B3 -> out B4
    k_prop<false><<<pb, 256, 0, stream>>>(B0, nullptr, 1.f, row_ptr, csr_src, csr_w, B1, N);
    k_prop<true ><<<pb, 256, 0, stream>>>(B1, B0, 2.f, row_ptr, csr_src, csr_w, B2, N);
    k_prop<true ><<<pb, 256, 0, stream>>>(B2, B1, 2.f, row_ptr, csr_src, csr_w, B3, N);
    k_gemm512<true><<<gb, 256, 0, stream>>>(B0, B1, B2, B3, W1, b1, B4, N);

    // layer 2: T0=B4, T1=B0, T2=B1, T3=B2 -> out B3
    k_prop<false><<<pb, 256, 0, stream>>>(B4, nullptr, 1.f, row_ptr, csr_src, csr_w, B0, N);
    k_prop<true ><<<pb, 256, 0, stream>>>(B0, B4, 2.f, row_ptr, csr_src, csr_w, B1, N);
    k_prop<true ><<<pb, 256, 0, stream>>>(B1, B0, 2.f, row_ptr, csr_src, csr_w, B2, N);
    k_gemm512<true><<<gb, 256, 0, stream>>>(B4, B0, B1, B2, W2, b2, B3, N);

    // heads -> d_out = [mu ; logvar]
    k_head<<<gb, 256, 0, stream>>>(B3, Wmu, bmu, Wlv, blv, (float*)d_out, N);
}

// Round 2
// 442.832 us; speedup vs baseline: 1.6853x; 1.6853x over previous
//
#include <hip/hip_runtime.h>

// ---------------------------------------------------------------------------
// SpectralEncoder: ChebConv(K=4) x2 + mu/logvar heads.  bf16 feature storage,
// MFMA (16x16x32 bf16) for all dense GEMMs, wave-per-node gather props.
// ---------------------------------------------------------------------------

typedef __bf16 bf16x8 __attribute__((ext_vector_type(8)));
typedef float f32x4 __attribute__((ext_vector_type(4)));
typedef unsigned int uint32;
typedef unsigned short ushort16;

__device__ inline ushort16 f2bf(float f) {            // RNE fp32 -> bf16
    uint32 x = __float_as_uint(f);
    uint32 r = x + 0x7fffu + ((x >> 16) & 1u);
    return (ushort16)(r >> 16);
}
__device__ inline float bflo(uint32 v) { return __uint_as_float(v << 16); }
__device__ inline float bfhi(uint32 v) { return __uint_as_float(v & 0xffff0000u); }

// ---------------- graph preprocessing (unchanged, fp32) --------------------

__global__ void k_deg_cnt(const int* __restrict__ src, const int* __restrict__ dst,
                          const float* __restrict__ ew, float* __restrict__ deg,
                          int* __restrict__ cnt, int E) {
    int e = blockIdx.x * blockDim.x + threadIdx.x;
    if (e >= E) return;
    atomicAdd(&deg[src[e]], ew[e]);
    atomicAdd(&cnt[dst[e]], 1);
}

__global__ void k_dis(const float* __restrict__ deg, float* __restrict__ dis, int N) {
    int i = blockIdx.x * blockDim.x + threadIdx.x;
    if (i >= N) return;
    float d = deg[i];
    dis[i] = d > 0.f ? rsqrtf(fmaxf(d, 1e-12f)) : 0.f;
}

__global__ void k_scan(const int* __restrict__ cnt, int* __restrict__ row_ptr,
                       int* __restrict__ cursor, int N) {
    __shared__ int sdata[1024];
    __shared__ int carry;
    int tid = threadIdx.x;
    if (tid == 0) carry = 0;
    __syncthreads();
    for (int base = 0; base < N; base += 1024) {
        int i = base + tid;
        int v = (i < N) ? cnt[i] : 0;
        sdata[tid] = v;
        __syncthreads();
        #pragma unroll
        for (int off = 1; off < 1024; off <<= 1) {
            int t = (tid >= off) ? sdata[tid - off] : 0;
            __syncthreads();
            sdata[tid] += t;
            __syncthreads();
        }
        int excl = carry + sdata[tid] - v;
        if (i < N) { row_ptr[i] = excl; cursor[i] = excl; }
        __syncthreads();
        if (tid == 1023) carry += sdata[1023];
        __syncthreads();
    }
    if (tid == 0) row_ptr[N] = carry;
}

__global__ void k_scatter(const int* __restrict__ src, const int* __restrict__ dst,
                          const float* __restrict__ ew, const float* __restrict__ dis,
                          int* __restrict__ cursor, int* __restrict__ csr_src,
                          float* __restrict__ csr_w, int E) {
    int e = blockIdx.x * blockDim.x + threadIdx.x;
    if (e >= E) return;
    int s = src[e], d = dst[e];
    float wv = -dis[s] * ew[e] * dis[d];
    int pos = atomicAdd(&cursor[d], 1);
    csr_src[pos] = s;
    csr_w[pos] = wv;
}

// ---------------- feature concat -> bf16 -----------------------------------

__global__ void k_concat_bf16(const float* __restrict__ x, const float* __restrict__ pe,
                              uint32* __restrict__ h, int N) {
    int i = blockIdx.x * blockDim.x + threadIdx.x;   // bf16-pair index
    if (i >= N * 64) return;
    int node = i >> 6, p = i & 63;
    float f0, f1;
    if (p < 56) { f0 = x[node * 112 + p * 2]; f1 = x[node * 112 + p * 2 + 1]; }
    else { int q = (p - 56) * 2; f0 = pe[node * 16 + q]; f1 = pe[node * 16 + q + 1]; }
    h[i] = (uint32)f2bf(f0) | ((uint32)f2bf(f1) << 16);
}

// ---------------- weight packing into MFMA B-fragment order ----------------
// B-frag (16x16x32): lane l holds B[k=(l>>4)*8+j][col=l&15], j=0..7 (16B).
// packed[((ks*8 + c)*64 + l)*8 + j] = W[ks*32 + (l>>4)*8 + j][c*16 + (l&15)]

__global__ void k_pack_w(const float* __restrict__ W, ushort16* __restrict__ Wp, int KS) {
    int t = blockIdx.x * blockDim.x + threadIdx.x;
    if (t >= KS * 8 * 64) return;
    int l = t & 63, c = (t >> 6) & 7, ks = t >> 9;
    int k0 = ks * 32 + (l >> 4) * 8;
    int col = c * 16 + (l & 15);
    uint4 o;
    uint32 v[8];
    #pragma unroll
    for (int j = 0; j < 8; ++j) v[j] = f2bf(W[(size_t)(k0 + j) * 128 + col]);
    o.x = v[0] | (v[1] << 16); o.y = v[2] | (v[3] << 16);
    o.z = v[4] | (v[5] << 16); o.w = v[6] | (v[7] << 16);
    *(uint4*)(Wp + (size_t)t * 8) = o;
}

__global__ void k_pack_head(const float* __restrict__ Wm, const float* __restrict__ Wl,
                            ushort16* __restrict__ Wp) {
    int t = blockIdx.x * blockDim.x + threadIdx.x;
    if (t >= 4 * 8 * 64) return;
    int l = t & 63, c = (t >> 6) & 7, ks = t >> 9;
    int k0 = ks * 32 + (l >> 4) * 8;
    int cc = c * 16 + (l & 15);
    const float* Ws = (cc < 64) ? Wm : Wl;
    int col = cc & 63;
    uint4 o;
    uint32 v[8];
    #pragma unroll
    for (int j = 0; j < 8; ++j) v[j] = f2bf(Ws[(size_t)(k0 + j) * 64 + col]);
    o.x = v[0] | (v[1] << 16); o.y = v[2] | (v[3] << 16);
    o.z = v[4] | (v[5] << 16); o.w = v[6] | (v[7] << 16);
    *(uint4*)(Wp + (size_t)t * 8) = o;
}

// ---------------- gather prop: out = scale*P*tin - sub  (bf16 features) ----
// one wave per node; lane covers 2 feats (4B loads, 256B/row coalesced).
// edge list preloaded into lanes, shfl-broadcast; 4 gathers in flight.

template<bool HAS_SUB>
__global__ void k_prop_bf16(const ushort16* __restrict__ tin, const ushort16* __restrict__ sub,
                            float scale, const int* __restrict__ row_ptr,
                            const int* __restrict__ csr_src, const float* __restrict__ csr_w,
                            uint32* __restrict__ out, int N) {
    int wid = (blockIdx.x * blockDim.x + threadIdx.x) >> 6;
    int lane = threadIdx.x & 63;
    if (wid >= N) return;
    int beg = row_ptr[wid], end = row_ptr[wid + 1];
    float ax = 0.f, ay = 0.f;
    for (int base = beg; base < end; base += 64) {
        int m = end - base; if (m > 64) m = 64;
        int si = 0; float wv = 0.f;
        if (lane < m) { si = csr_src[base + lane]; wv = csr_w[base + lane]; }
        int j = 0;
        for (; j + 3 < m; j += 4) {
            int s0 = __shfl(si, j),     s1 = __shfl(si, j + 1);
            int s2 = __shfl(si, j + 2), s3 = __shfl(si, j + 3);
            float w0 = __shfl(wv, j),     w1 = __shfl(wv, j + 1);
            float w2 = __shfl(wv, j + 2), w3 = __shfl(wv, j + 3);
            uint32 v0 = *(const uint32*)((const ushort16*)tin + (size_t)s0 * 128 + lane * 2);
            uint32 v1 = *(const uint32*)((const ushort16*)tin + (size_t)s1 * 128 + lane * 2);
            uint32 v2 = *(const uint32*)((const ushort16*)tin + (size_t)s2 * 128 + lane * 2);
            uint32 v3 = *(const uint32*)((const ushort16*)tin + (size_t)s3 * 128 + lane * 2);
            ax = fmaf(w0, bflo(v0), ax); ay = fmaf(w0, bfhi(v0), ay);
            ax = fmaf(w1, bflo(v1), ax); ay = fmaf(w1, bfhi(v1), ay);
            ax = fmaf(w2, bflo(v2), ax); ay = fmaf(w2, bfhi(v2), ay);
            ax = fmaf(w3, bflo(v3), ax); ay = fmaf(w3, bfhi(v3), ay);
        }
        for (; j < m; ++j) {
            int s0 = __shfl(si, j);
            float w0 = __shfl(wv, j);
            uint32 v0 = *(const uint32*)((const ushort16*)tin + (size_t)s0 * 128 + lane * 2);
            ax = fmaf(w0, bflo(v0), ax); ay = fmaf(w0, bfhi(v0), ay);
        }
    }
    float ox = scale * ax, oy = scale * ay;
    if (HAS_SUB) {
        uint32 sv = *(const uint32*)((const ushort16*)sub + (size_t)wid * 128 + lane * 2);
        ox -= bflo(sv); oy -= bfhi(sv);
    }
    out[(size_t)wid * 64 + lane] = (uint32)f2bf(ox) | ((uint32)f2bf(oy) << 16);
}

// ---------------- MFMA GEMM: C[N,128] = relu(sum_t T_t @ W_t + b), K=512 ---
// 256 thr = 4 waves; wave owns 32 rows (2 m-frags) x 128 cols (8 n-frags).
// A-frags direct from global (16B/lane row loads); B pre-packed, L2-hot.

template<bool RELU>
__launch_bounds__(256)
__global__ void k_mfma_gemm512(const ushort16* __restrict__ t0, const ushort16* __restrict__ t1,
                               const ushort16* __restrict__ t2, const ushort16* __restrict__ t3,
                               const ushort16* __restrict__ Wp, const float* __restrict__ bias,
                               ushort16* __restrict__ C, int N) {
    const int lane = threadIdx.x & 63;
    const int wave = threadIdx.x >> 6;
    const int brow = blockIdx.x * 128 + wave * 32;
    int r0 = brow + (lane & 15);
    int r1 = r0 + 16;
    if (r0 >= N) r0 = N - 1;
    if (r1 >= N) r1 = N - 1;
    const int kg8 = (lane >> 4) * 8;
    f32x4 acc[2][8] = {};
    #pragma unroll
    for (int t = 0; t < 4; ++t) {
        const ushort16* __restrict__ A = (t == 0) ? t0 : (t == 1) ? t1 : (t == 2) ? t2 : t3;
        const ushort16* a0p = A + (size_t)r0 * 128 + kg8;
        const ushort16* a1p = A + (size_t)r1 * 128 + kg8;
        #pragma unroll
        for (int ks2 = 0; ks2 < 4; ++ks2) {
            bf16x8 a0 = *(const bf16x8*)(a0p + ks2 * 32);
            bf16x8 a1 = *(const bf16x8*)(a1p + ks2 * 32);
            const ushort16* bp = Wp + (size_t)((t * 4 + ks2) * 8 * 64 + lane) * 8;
            #pragma unroll
            for (int c = 0; c < 8; ++c) {
                bf16x8 b = *(const bf16x8*)(bp + c * 512);
                acc[0][c] = __builtin_amdgcn_mfma_f32_16x16x32_bf16(a0, b, acc[0][c], 0, 0, 0);
                acc[1][c] = __builtin_amdgcn_mfma_f32_16x16x32_bf16(a1, b, acc[1][c], 0, 0, 0);
            }
        }
    }
    const int col0 = lane & 15;
    const int rj = (lane >> 4) * 4;
    #pragma unroll
    for (int m = 0; m < 2; ++m) {
        #pragma unroll
        for (int c = 0; c < 8; ++c) {
            float bv = bias[c * 16 + col0];
            #pragma unroll
            for (int j = 0; j < 4; ++j) {
                int row = brow + m * 16 + rj + j;
                if (row < N) {
                    float v = acc[m][c][j] + bv;
                    if (RELU) v = fmaxf(v, 0.f);
                    C[(size_t)row * 128 + c * 16 + col0] = f2bf(v);
                }
            }
        }
    }
}

// ---------------- fused heads via MFMA: [N,128]@[128,128], cols=[mu|lv] ----

__launch_bounds__(256)
__global__ void k_mfma_head(const ushort16* __restrict__ A, const ushort16* __restrict__ Wp,
                            const float* __restrict__ bm, const float* __restrict__ bl,
                            float* __restrict__ out, int N) {
    const int lane = threadIdx.x & 63;
    const int wave = threadIdx.x >> 6;
    const int brow = blockIdx.x * 128 + wave * 32;
    int r0 = brow + (lane & 15);
    int r1 = r0 + 16;
    if (r0 >= N) r0 = N - 1;
    if (r1 >= N) r1 = N - 1;
    const int kg8 = (lane >> 4) * 8;
    f32x4 acc[2][8] = {};
    const ushort16* a0p = A + (size_t)r0 * 128 + kg8;
    const ushort16* a1p = A + (size_t)r1 * 128 + kg8;
    #pragma unroll
    for (int ks = 0; ks < 4; ++ks) {
        bf16x8 a0 = *(const bf16x8*)(a0p + ks * 32);
        bf16x8 a1 = *(const bf16x8*)(a1p + ks * 32);
        const ushort16* bp = Wp + (size_t)(ks * 8 * 64 + lane) * 8;
        #pragma unroll
        for (int c = 0; c < 8; ++c) {
            bf16x8 b = *(const bf16x8*)(bp + c * 512);
            acc[0][c] = __builtin_amdgcn_mfma_f32_16x16x32_bf16(a0, b, acc[0][c], 0, 0, 0);
            acc[1][c] = __builtin_amdgcn_mfma_f32_16x16x32_bf16(a1, b, acc[1][c], 0, 0, 0);
        }
    }
    const int col0 = lane & 15;
    const int rj = (lane >> 4) * 4;
    #pragma unroll
    for (int m = 0; m < 2; ++m) {
        #pragma unroll
        for (int c = 0; c < 8; ++c) {
            int gcol = (c & 3) * 16 + col0;                 // 0..63 within head
            float bv = (c < 4) ? bm[gcol] : bl[gcol];
            size_t hoff = (c < 4) ? 0 : (size_t)N * 64;
            #pragma unroll
            for (int j = 0; j < 4; ++j) {
                int row = brow + m * 16 + rj + j;
                if (row < N)
                    out[hoff + (size_t)row * 64 + gcol] = acc[m][c][j] + bv;
            }
        }
    }
}

// ---------------------------------------------------------------------------

extern "C" void kernel_launch(void* const* d_in, const int* in_sizes, int n_in,
                              void* d_out, int out_size, void* d_ws, size_t ws_size,
                              hipStream_t stream) {
    const float* x   = (const float*)d_in[0];
    const int*   ei  = (const int*)d_in[1];
    const float* pe  = (const float*)d_in[2];
    const float* ew  = (const float*)d_in[3];
    const float* W1  = (const float*)d_in[4];
    const float* b1  = (const float*)d_in[5];
    const float* W2  = (const float*)d_in[6];
    const float* b2  = (const float*)d_in[7];
    const float* Wmu = (const float*)d_in[8];
    const float* bmu = (const float*)d_in[9];
    const float* Wlv = (const float*)d_in[10];
    const float* blv = (const float*)d_in[11];

    const int N = in_sizes[0] / 112;
    const int E = in_sizes[1] / 2;
    const int* src = ei;
    const int* dst = ei + E;

    char* ws = (char*)d_ws;
    size_t off = 0;
    auto alloc = [&](size_t bytes) -> char* {
        char* p = ws + off;
        off = (off + bytes + 255) & ~(size_t)255;
        return p;
    };
    float* deg     = (float*)alloc((size_t)N * 4);
    int*   cnt     = (int*)  alloc((size_t)N * 4);
    float* dis     = (float*)alloc((size_t)N * 4);
    int*   row_ptr = (int*)  alloc((size_t)(N + 1) * 4);
    int*   cursor  = (int*)  alloc((size_t)N * 4);
    int*   csr_src = (int*)  alloc((size_t)E * 4);
    float* csr_w   = (float*)alloc((size_t)E * 4);
    ushort16* W1p  = (ushort16*)alloc((size_t)512 * 128 * 2);
    ushort16* W2p  = (ushort16*)alloc((size_t)512 * 128 * 2);
    ushort16* WHp  = (ushort16*)alloc((size_t)128 * 128 * 2);
    ushort16* B0 = (ushort16*)alloc((size_t)N * 128 * 2);
    ushort16* B1 = (ushort16*)alloc((size_t)N * 128 * 2);
    ushort16* B2 = (ushort16*)alloc((size_t)N * 128 * 2);
    ushort16* B3 = (ushort16*)alloc((size_t)N * 128 * 2);
    ushort16* B4 = (ushort16*)alloc((size_t)N * 128 * 2);

    hipMemsetAsync(deg, 0, (size_t)N * 4, stream);
    hipMemsetAsync(cnt, 0, (size_t)N * 4, stream);

    const int eb = (E + 255) / 256;
    const int nb = (N + 255) / 256;
    const int pb = (N + 3) / 4;        // wave-per-node, 4 waves/block
    const int gb = (N + 127) / 128;    // 128 rows/block MFMA tiles

    k_deg_cnt<<<eb, 256, 0, stream>>>(src, dst, ew, deg, cnt, E);
    k_dis<<<nb, 256, 0, stream>>>(deg, dis, N);
    k_scan<<<1, 1024, 0, stream>>>(cnt, row_ptr, cursor, N);
    k_scatter<<<eb, 256, 0, stream>>>(src, dst, ew, dis, cursor, csr_src, csr_w, E);
    k_concat_bf16<<<(N * 64 + 255) / 256, 256, 0, stream>>>(x, pe, (uint32*)B0, N);
    k_pack_w<<<(16 * 8 * 64 + 255) / 256, 256, 0, stream>>>(W1, W1p, 16);
    k_pack_w<<<(16 * 8 * 64 + 255) / 256, 256, 0, stream>>>(W2, W2p, 16);
    k_pack_head<<<(4 * 8 * 64 + 255) / 256, 256, 0, stream>>>(Wmu, Wlv, WHp);

    // layer 1: T0=B0, T1=B1, T2=B2, T3=B3 -> relu gemm -> B4
    k_prop_bf16<false><<<pb, 256, 0, stream>>>(B0, nullptr, 1.f, row_ptr, csr_src, csr_w, (uint32*)B1, N);
    k_prop_bf16<true ><<<pb, 256, 0, stream>>>(B1, B0, 2.f, row_ptr, csr_src, csr_w, (uint32*)B2, N);
    k_prop_bf16<true ><<<pb, 256, 0, stream>>>(B2, B1, 2.f, row_ptr, csr_src, csr_w, (uint32*)B3, N);
    k_mfma_gemm512<true><<<gb, 256, 0, stream>>>(B0, B1, B2, B3, W1p, b1, B4, N);

    // layer 2: T0=B4, T1=B0, T2=B1, T3=B2 -> relu gemm -> B3
    k_prop_bf16<false><<<pb, 256, 0, stream>>>(B4, nullptr, 1.f, row_ptr, csr_src, csr_w, (uint32*)B0, N);
    k_prop_bf16<true ><<<pb, 256, 0, stream>>>(B0, B4, 2.f, row_ptr, csr_src, csr_w, (uint32*)B1, N);
    k_prop_bf16<true ><<<pb, 256, 0, stream>>>(B1, B0, 2.f, row_ptr, csr_src, csr_w, (uint32*)B2, N);
    k_mfma_gemm512<true><<<gb, 256, 0, stream>>>(B4, B0, B1, B2, W2p, b2, B3, N);

    // heads -> d_out = [mu ; logvar] fp32
    k_mfma_head<<<gb, 256, 0, stream>>>(B3, WHp, bmu, blv, (float*)d_out, N);
}

// Round 3
// 356.972 us; speedup vs baseline: 2.0907x; 1.2405x over previous
//
#include <hip/hip_runtime.h>

// ---------------------------------------------------------------------------
// SpectralEncoder: ChebConv(K=4) x2 + mu/logvar heads.  bf16 feature storage,
// MFMA (16x16x32 bf16) for all dense GEMMs, wave-per-node gather props.
// R2: replaced single-block scan (94us, 1 CU) with 3-phase multi-block scan.
// ---------------------------------------------------------------------------

typedef __bf16 bf16x8 __attribute__((ext_vector_type(8)));
typedef float f32x4 __attribute__((ext_vector_type(4)));
typedef unsigned int uint32;
typedef unsigned short ushort16;

__device__ inline ushort16 f2bf(float f) {            // RNE fp32 -> bf16
    uint32 x = __float_as_uint(f);
    uint32 r = x + 0x7fffu + ((x >> 16) & 1u);
    return (ushort16)(r >> 16);
}
__device__ inline float bflo(uint32 v) { return __uint_as_float(v << 16); }
__device__ inline float bfhi(uint32 v) { return __uint_as_float(v & 0xffff0000u); }

// ---------------- graph preprocessing --------------------------------------

__global__ void k_deg_cnt(const int* __restrict__ src, const int* __restrict__ dst,
                          const float* __restrict__ ew, float* __restrict__ deg,
                          int* __restrict__ cnt, int E) {
    int e = blockIdx.x * blockDim.x + threadIdx.x;
    if (e >= E) return;
    atomicAdd(&deg[src[e]], ew[e]);
    atomicAdd(&cnt[dst[e]], 1);
}

__global__ void k_dis(const float* __restrict__ deg, float* __restrict__ dis, int N) {
    int i = blockIdx.x * blockDim.x + threadIdx.x;
    if (i >= N) return;
    float d = deg[i];
    dis[i] = d > 0.f ? rsqrtf(fmaxf(d, 1e-12f)) : 0.f;
}

// --- 3-phase exclusive scan of cnt[0..N) -> row_ptr, cursor ---------------
// A: 256 thr/block scan 1024 elems (int4/thread), write local prefixes + total
__global__ void k_scan_blk(const int* __restrict__ cnt, int* __restrict__ row_ptr,
                           int* __restrict__ blk_sums, int N) {
    __shared__ int wsum[4];
    const int tid = threadIdx.x;
    const int base = blockIdx.x * 1024 + tid * 4;
    int4 v = make_int4(0, 0, 0, 0);
    if (base + 3 < N) v = *(const int4*)&cnt[base];
    else {
        if (base + 0 < N) v.x = cnt[base + 0];
        if (base + 1 < N) v.y = cnt[base + 1];
        if (base + 2 < N) v.z = cnt[base + 2];
    }
    const int tsum = v.x + v.y + v.z + v.w;
    const int lane = tid & 63;
    const int wv = tid >> 6;
    int incl = tsum;
    #pragma unroll
    for (int off = 1; off < 64; off <<= 1) {
        int t = __shfl_up(incl, off);
        if (lane >= off) incl += t;
    }
    if (lane == 63) wsum[wv] = incl;
    __syncthreads();
    int woff = 0;
    #pragma unroll
    for (int w = 0; w < 4; ++w) if (w < wv) woff += wsum[w];
    const int excl = woff + incl - tsum;
    if (base + 0 < N) row_ptr[base + 0] = excl;
    if (base + 1 < N) row_ptr[base + 1] = excl + v.x;
    if (base + 2 < N) row_ptr[base + 2] = excl + v.x + v.y;
    if (base + 3 < N) row_ptr[base + 3] = excl + v.x + v.y + v.z;
    if (tid == 255) blk_sums[blockIdx.x] = woff + incl;
}

// B: one wave scans block totals (nblk <= 64), writes row_ptr[N]=E_total
__global__ void k_scan_top(int* __restrict__ blk_sums, int* __restrict__ row_ptr,
                           int nblk, int N) {
    const int lane = threadIdx.x;
    int v = (lane < nblk) ? blk_sums[lane] : 0;
    int incl = v;
    #pragma unroll
    for (int off = 1; off < 64; off <<= 1) {
        int t = __shfl_up(incl, off);
        if (lane >= off) incl += t;
    }
    if (lane < nblk) blk_sums[lane] = incl - v;   // exclusive block offset
    if (lane == 63) row_ptr[N] = incl;            // grand total
}

// C: add block offsets, mirror into cursor
__global__ void k_scan_fix(int* __restrict__ row_ptr, int* __restrict__ cursor,
                           const int* __restrict__ blk_sums, int N) {
    int i = blockIdx.x * blockDim.x + threadIdx.x;
    if (i >= N) return;
    int v = row_ptr[i] + blk_sums[i >> 10];
    row_ptr[i] = v;
    cursor[i] = v;
}

__global__ void k_scatter(const int* __restrict__ src, const int* __restrict__ dst,
                          const float* __restrict__ ew, const float* __restrict__ dis,
                          int* __restrict__ cursor, int* __restrict__ csr_src,
                          float* __restrict__ csr_w, int E) {
    int e = blockIdx.x * blockDim.x + threadIdx.x;
    if (e >= E) return;
    int s = src[e], d = dst[e];
    float wv = -dis[s] * ew[e] * dis[d];
    int pos = atomicAdd(&cursor[d], 1);
    csr_src[pos] = s;
    csr_w[pos] = wv;
}

// ---------------- feature concat -> bf16 -----------------------------------

__global__ void k_concat_bf16(const float* __restrict__ x, const float* __restrict__ pe,
                              uint32* __restrict__ h, int N) {
    int i = blockIdx.x * blockDim.x + threadIdx.x;   // bf16-pair index
    if (i >= N * 64) return;
    int node = i >> 6, p = i & 63;
    float f0, f1;
    if (p < 56) { f0 = x[node * 112 + p * 2]; f1 = x[node * 112 + p * 2 + 1]; }
    else { int q = (p - 56) * 2; f0 = pe[node * 16 + q]; f1 = pe[node * 16 + q + 1]; }
    h[i] = (uint32)f2bf(f0) | ((uint32)f2bf(f1) << 16);
}

// ---------------- weight packing into MFMA B-fragment order ----------------
// B-frag (16x16x32): lane l holds B[k=(l>>4)*8+j][col=l&15], j=0..7 (16B).

__global__ void k_pack_w(const float* __restrict__ W, ushort16* __restrict__ Wp, int KS) {
    int t = blockIdx.x * blockDim.x + threadIdx.x;
    if (t >= KS * 8 * 64) return;
    int l = t & 63, c = (t >> 6) & 7, ks = t >> 9;
    int k0 = ks * 32 + (l >> 4) * 8;
    int col = c * 16 + (l & 15);
    uint4 o;
    uint32 v[8];
    #pragma unroll
    for (int j = 0; j < 8; ++j) v[j] = f2bf(W[(size_t)(k0 + j) * 128 + col]);
    o.x = v[0] | (v[1] << 16); o.y = v[2] | (v[3] << 16);
    o.z = v[4] | (v[5] << 16); o.w = v[6] | (v[7] << 16);
    *(uint4*)(Wp + (size_t)t * 8) = o;
}

__global__ void k_pack_head(const float* __restrict__ Wm, const float* __restrict__ Wl,
                            ushort16* __restrict__ Wp) {
    int t = blockIdx.x * blockDim.x + threadIdx.x;
    if (t >= 4 * 8 * 64) return;
    int l = t & 63, c = (t >> 6) & 7, ks = t >> 9;
    int k0 = ks * 32 + (l >> 4) * 8;
    int cc = c * 16 + (l & 15);
    const float* Ws = (cc < 64) ? Wm : Wl;
    int col = cc & 63;
    uint4 o;
    uint32 v[8];
    #pragma unroll
    for (int j = 0; j < 8; ++j) v[j] = f2bf(Ws[(size_t)(k0 + j) * 64 + col]);
    o.x = v[0] | (v[1] << 16); o.y = v[2] | (v[3] << 16);
    o.z = v[4] | (v[5] << 16); o.w = v[6] | (v[7] << 16);
    *(uint4*)(Wp + (size_t)t * 8) = o;
}

// ---------------- gather prop: out = scale*P*tin - sub  (bf16 features) ----

template<bool HAS_SUB>
__global__ void k_prop_bf16(const ushort16* __restrict__ tin, const ushort16* __restrict__ sub,
                            float scale, const int* __restrict__ row_ptr,
                            const int* __restrict__ csr_src, const float* __restrict__ csr_w,
                            uint32* __restrict__ out, int N) {
    int wid = (blockIdx.x * blockDim.x + threadIdx.x) >> 6;
    int lane = threadIdx.x & 63;
    if (wid >= N) return;
    int beg = row_ptr[wid], end = row_ptr[wid + 1];
    float ax = 0.f, ay = 0.f;
    for (int base = beg; base < end; base += 64) {
        int m = end - base; if (m > 64) m = 64;
        int si = 0; float wv = 0.f;
        if (lane < m) { si = csr_src[base + lane]; wv = csr_w[base + lane]; }
        int j = 0;
        for (; j + 3 < m; j += 4) {
            int s0 = __shfl(si, j),     s1 = __shfl(si, j + 1);
            int s2 = __shfl(si, j + 2), s3 = __shfl(si, j + 3);
            float w0 = __shfl(wv, j),     w1 = __shfl(wv, j + 1);
            float w2 = __shfl(wv, j + 2), w3 = __shfl(wv, j + 3);
            uint32 v0 = *(const uint32*)((const ushort16*)tin + (size_t)s0 * 128 + lane * 2);
            uint32 v1 = *(const uint32*)((const ushort16*)tin + (size_t)s1 * 128 + lane * 2);
            uint32 v2 = *(const uint32*)((const ushort16*)tin + (size_t)s2 * 128 + lane * 2);
            uint32 v3 = *(const uint32*)((const ushort16*)tin + (size_t)s3 * 128 + lane * 2);
            ax = fmaf(w0, bflo(v0), ax); ay = fmaf(w0, bfhi(v0), ay);
            ax = fmaf(w1, bflo(v1), ax); ay = fmaf(w1, bfhi(v1), ay);
            ax = fmaf(w2, bflo(v2), ax); ay = fmaf(w2, bfhi(v2), ay);
            ax = fmaf(w3, bflo(v3), ax); ay = fmaf(w3, bfhi(v3), ay);
        }
        for (; j < m; ++j) {
            int s0 = __shfl(si, j);
            float w0 = __shfl(wv, j);
            uint32 v0 = *(const uint32*)((const ushort16*)tin + (size_t)s0 * 128 + lane * 2);
            ax = fmaf(w0, bflo(v0), ax); ay = fmaf(w0, bfhi(v0), ay);
        }
    }
    float ox = scale * ax, oy = scale * ay;
    if (HAS_SUB) {
        uint32 sv = *(const uint32*)((const ushort16*)sub + (size_t)wid * 128 + lane * 2);
        ox -= bflo(sv); oy -= bfhi(sv);
    }
    out[(size_t)wid * 64 + lane] = (uint32)f2bf(ox) | ((uint32)f2bf(oy) << 16);
}

// ---------------- MFMA GEMM: C[N,128] = relu(sum_t T_t @ W_t + b), K=512 ---

template<bool RELU>
__launch_bounds__(256)
__global__ void k_mfma_gemm512(const ushort16* __restrict__ t0, const ushort16* __restrict__ t1,
                               const ushort16* __restrict__ t2, const ushort16* __restrict__ t3,
                               const ushort16* __restrict__ Wp, const float* __restrict__ bias,
                               ushort16* __restrict__ C, int N) {
    const int lane = threadIdx.x & 63;
    const int wave = threadIdx.x >> 6;
    const int brow = blockIdx.x * 128 + wave * 32;
    int r0 = brow + (lane & 15);
    int r1 = r0 + 16;
    if (r0 >= N) r0 = N - 1;
    if (r1 >= N) r1 = N - 1;
    const int kg8 = (lane >> 4) * 8;
    f32x4 acc[2][8] = {};
    #pragma unroll
    for (int t = 0; t < 4; ++t) {
        const ushort16* __restrict__ A = (t == 0) ? t0 : (t == 1) ? t1 : (t == 2) ? t2 : t3;
        const ushort16* a0p = A + (size_t)r0 * 128 + kg8;
        const ushort16* a1p = A + (size_t)r1 * 128 + kg8;
        #pragma unroll
        for (int ks2 = 0; ks2 < 4; ++ks2) {
            bf16x8 a0 = *(const bf16x8*)(a0p + ks2 * 32);
            bf16x8 a1 = *(const bf16x8*)(a1p + ks2 * 32);
            const ushort16* bp = Wp + (size_t)((t * 4 + ks2) * 8 * 64 + lane) * 8;
            #pragma unroll
            for (int c = 0; c < 8; ++c) {
                bf16x8 b = *(const bf16x8*)(bp + c * 512);
                acc[0][c] = __builtin_amdgcn_mfma_f32_16x16x32_bf16(a0, b, acc[0][c], 0, 0, 0);
                acc[1][c] = __builtin_amdgcn_mfma_f32_16x16x32_bf16(a1, b, acc[1][c], 0, 0, 0);
            }
        }
    }
    const int col0 = lane & 15;
    const int rj = (lane >> 4) * 4;
    #pragma unroll
    for (int m = 0; m < 2; ++m) {
        #pragma unroll
        for (int c = 0; c < 8; ++c) {
            float bv = bias[c * 16 + col0];
            #pragma unroll
            for (int j = 0; j < 4; ++j) {
                int row = brow + m * 16 + rj + j;
                if (row < N) {
                    float v = acc[m][c][j] + bv;
                    if (RELU) v = fmaxf(v, 0.f);
                    C[(size_t)row * 128 + c * 16 + col0] = f2bf(v);
                }
            }
        }
    }
}

// ---------------- fused heads via MFMA: [N,128]@[128,128], cols=[mu|lv] ----

__launch_bounds__(256)
__global__ void k_mfma_head(const ushort16* __restrict__ A, const ushort16* __restrict__ Wp,
                            const float* __restrict__ bm, const float* __restrict__ bl,
                            float* __restrict__ out, int N) {
    const int lane = threadIdx.x & 63;
    const int wave = threadIdx.x >> 6;
    const int brow = blockIdx.x * 128 + wave * 32;
    int r0 = brow + (lane & 15);
    int r1 = r0 + 16;
    if (r0 >= N) r0 = N - 1;
    if (r1 >= N) r1 = N - 1;
    const int kg8 = (lane >> 4) * 8;
    f32x4 acc[2][8] = {};
    const ushort16* a0p = A + (size_t)r0 * 128 + kg8;
    const ushort16* a1p = A + (size_t)r1 * 128 + kg8;
    #pragma unroll
    for (int ks = 0; ks < 4; ++ks) {
        bf16x8 a0 = *(const bf16x8*)(a0p + ks * 32);
        bf16x8 a1 = *(const bf16x8*)(a1p + ks * 32);
        const ushort16* bp = Wp + (size_t)(ks * 8 * 64 + lane) * 8;
        #pragma unroll
        for (int c = 0; c < 8; ++c) {
            bf16x8 b = *(const bf16x8*)(bp + c * 512);
            acc[0][c] = __builtin_amdgcn_mfma_f32_16x16x32_bf16(a0, b, acc[0][c], 0, 0, 0);
            acc[1][c] = __builtin_amdgcn_mfma_f32_16x16x32_bf16(a1, b, acc[1][c], 0, 0, 0);
        }
    }
    const int col0 = lane & 15;
    const int rj = (lane >> 4) * 4;
    #pragma unroll
    for (int m = 0; m < 2; ++m) {
        #pragma unroll
        for (int c = 0; c < 8; ++c) {
            int gcol = (c & 3) * 16 + col0;                 // 0..63 within head
            float bv = (c < 4) ? bm[gcol] : bl[gcol];
            size_t hoff = (c < 4) ? 0 : (size_t)N * 64;
            #pragma unroll
            for (int j = 0; j < 4; ++j) {
                int row = brow + m * 16 + rj + j;
                if (row < N)
                    out[hoff + (size_t)row * 64 + gcol] = acc[m][c][j] + bv;
            }
        }
    }
}

// ---------------------------------------------------------------------------

extern "C" void kernel_launch(void* const* d_in, const int* in_sizes, int n_in,
                              void* d_out, int out_size, void* d_ws, size_t ws_size,
                              hipStream_t stream) {
    const float* x   = (const float*)d_in[0];
    const int*   ei  = (const int*)d_in[1];
    const float* pe  = (const float*)d_in[2];
    const float* ew  = (const float*)d_in[3];
    const float* W1  = (const float*)d_in[4];
    const float* b1  = (const float*)d_in[5];
    const float* W2  = (const float*)d_in[6];
    const float* b2  = (const float*)d_in[7];
    const float* Wmu = (const float*)d_in[8];
    const float* bmu = (const float*)d_in[9];
    const float* Wlv = (const float*)d_in[10];
    const float* blv = (const float*)d_in[11];

    const int N = in_sizes[0] / 112;
    const int E = in_sizes[1] / 2;
    const int* src = ei;
    const int* dst = ei + E;

    char* ws = (char*)d_ws;
    size_t off = 0;
    auto alloc = [&](size_t bytes) -> char* {
        char* p = ws + off;
        off = (off + bytes + 255) & ~(size_t)255;
        return p;
    };
    float* deg     = (float*)alloc((size_t)N * 4);
    int*   cnt     = (int*)  alloc((size_t)N * 4);
    float* dis     = (float*)alloc((size_t)N * 4);
    int*   row_ptr = (int*)  alloc((size_t)(N + 1) * 4);
    int*   cursor  = (int*)  alloc((size_t)N * 4);
    int*   blk_sums= (int*)  alloc((size_t)256 * 4);
    int*   csr_src = (int*)  alloc((size_t)E * 4);
    float* csr_w   = (float*)alloc((size_t)E * 4);
    ushort16* W1p  = (ushort16*)alloc((size_t)512 * 128 * 2);
    ushort16* W2p  = (ushort16*)alloc((size_t)512 * 128 * 2);
    ushort16* WHp  = (ushort16*)alloc((size_t)128 * 128 * 2);
    ushort16* B0 = (ushort16*)alloc((size_t)N * 128 * 2);
    ushort16* B1 = (ushort16*)alloc((size_t)N * 128 * 2);
    ushort16* B2 = (ushort16*)alloc((size_t)N * 128 * 2);
    ushort16* B3 = (ushort16*)alloc((size_t)N * 128 * 2);
    ushort16* B4 = (ushort16*)alloc((size_t)N * 128 * 2);

    hipMemsetAsync(deg, 0, (size_t)N * 4, stream);
    hipMemsetAsync(cnt, 0, (size_t)N * 4, stream);

    const int eb = (E + 255) / 256;
    const int nb = (N + 255) / 256;
    const int pb = (N + 3) / 4;        // wave-per-node, 4 waves/block
    const int gb = (N + 127) / 128;    // 128 rows/block MFMA tiles
    const int nblk = (N + 1023) / 1024;  // 49 for N=50000 (<= 64 required)

    k_deg_cnt<<<eb, 256, 0, stream>>>(src, dst, ew, deg, cnt, E);
    k_dis<<<nb, 256, 0, stream>>>(deg, dis, N);
    k_scan_blk<<<nblk, 256, 0, stream>>>(cnt, row_ptr, blk_sums, N);
    k_scan_top<<<1, 64, 0, stream>>>(blk_sums, row_ptr, nblk, N);
    k_scan_fix<<<nb, 256, 0, stream>>>(row_ptr, cursor, blk_sums, N);
    k_scatter<<<eb, 256, 0, stream>>>(src, dst, ew, dis, cursor, csr_src, csr_w, E);
    k_concat_bf16<<<(N * 64 + 255) / 256, 256, 0, stream>>>(x, pe, (uint32*)B0, N);
    k_pack_w<<<(16 * 8 * 64 + 255) / 256, 256, 0, stream>>>(W1, W1p, 16);
    k_pack_w<<<(16 * 8 * 64 + 255) / 256, 256, 0, stream>>>(W2, W2p, 16);
    k_pack_head<<<(4 * 8 * 64 + 255) / 256, 256, 0, stream>>>(Wmu, Wlv, WHp);

    // layer 1: T0=B0, T1=B1, T2=B2, T3=B3 -> relu gemm -> B4
    k_prop_bf16<false><<<pb, 256, 0, stream>>>(B0, nullptr, 1.f, row_ptr, csr_src, csr_w, (uint32*)B1, N);
    k_prop_bf16<true ><<<pb, 256, 0, stream>>>(B1, B0, 2.f, row_ptr, csr_src, csr_w, (uint32*)B2, N);
    k_prop_bf16<true ><<<pb, 256, 0, stream>>>(B2, B1, 2.f, row_ptr, csr_src, csr_w, (uint32*)B3, N);
    k_mfma_gemm512<true><<<gb, 256, 0, stream>>>(B0, B1, B2, B3, W1p, b1, B4, N);

    // layer 2: T0=B4, T1=B0, T2=B1, T3=B2 -> relu gemm -> B3
    k_prop_bf16<false><<<pb, 256, 0, stream>>>(B4, nullptr, 1.f, row_ptr, csr_src, csr_w, (uint32*)B0, N);
    k_prop_bf16<true ><<<pb, 256, 0, stream>>>(B0, B4, 2.f, row_ptr, csr_src, csr_w, (uint32*)B1, N);
    k_prop_bf16<true ><<<pb, 256, 0, stream>>>(B1, B0, 2.f, row_ptr, csr_src, csr_w, (uint32*)B2, N);
    k_mfma_gemm512<true><<<gb, 256, 0, stream>>>(B4, B0, B1, B2, W2p, b2, B3, N);

    // heads -> d_out = [mu ; logvar] fp32
    k_mfma_head<<<gb, 256, 0, stream>>>(B3, WHp, bmu, blv, (float*)d_out, N);
}

// Round 4
// 306.201 us; speedup vs baseline: 2.4373x; 1.1658x over previous
//
#include <hip/hip_runtime.h>

// ---------------------------------------------------------------------------
// SpectralEncoder: ChebConv(K=4) x2 + mu/logvar heads.  bf16 features, MFMA
// GEMMs, wave-per-node gather props.
// R3: atomic-free scatter (pos reservation in deg_cnt), Chebyshev recurrence
//     folded into packed weights (props are pure P*x), int2 csr + 8-deep
//     gather unroll, fused small kernels.
// ---------------------------------------------------------------------------

typedef __bf16 bf16x8 __attribute__((ext_vector_type(8)));
typedef float f32x4 __attribute__((ext_vector_type(4)));
typedef unsigned int uint32;
typedef unsigned short ushort16;

__device__ inline ushort16 f2bf(float f) {            // RNE fp32 -> bf16
    uint32 x = __float_as_uint(f);
    uint32 r = x + 0x7fffu + ((x >> 16) & 1u);
    return (ushort16)(r >> 16);
}
__device__ inline float bflo(uint32 v) { return __uint_as_float(v << 16); }
__device__ inline float bfhi(uint32 v) { return __uint_as_float(v & 0xffff0000u); }

// ---------------- graph preprocessing --------------------------------------
// deg atomics (src-keyed) + cnt atomics (dst-keyed) with position reservation.

__global__ void k_deg_cnt(const int* __restrict__ src, const int* __restrict__ dst,
                          const float* __restrict__ ew, float* __restrict__ deg,
                          int* __restrict__ cnt, int* __restrict__ pos, int E) {
    int e = blockIdx.x * blockDim.x + threadIdx.x;
    if (e >= E) return;
    atomicAdd(&deg[src[e]], ew[e]);
    pos[e] = atomicAdd(&cnt[dst[e]], 1);
}

// --- scan phase A: 256 thr/block scan 1024 elems, local prefixes + total ---
__global__ void k_scan_blk(const int* __restrict__ cnt, int* __restrict__ row_ptr,
                           int* __restrict__ blk_sums, int N) {
    __shared__ int wsum[4];
    const int tid = threadIdx.x;
    const int base = blockIdx.x * 1024 + tid * 4;
    int4 v = make_int4(0, 0, 0, 0);
    if (base + 3 < N) v = *(const int4*)&cnt[base];
    else {
        if (base + 0 < N) v.x = cnt[base + 0];
        if (base + 1 < N) v.y = cnt[base + 1];
        if (base + 2 < N) v.z = cnt[base + 2];
    }
    const int tsum = v.x + v.y + v.z + v.w;
    const int lane = tid & 63;
    const int wv = tid >> 6;
    int incl = tsum;
    #pragma unroll
    for (int off = 1; off < 64; off <<= 1) {
        int t = __shfl_up(incl, off);
        if (lane >= off) incl += t;
    }
    if (lane == 63) wsum[wv] = incl;
    __syncthreads();
    int woff = 0;
    #pragma unroll
    for (int w = 0; w < 4; ++w) if (w < wv) woff += wsum[w];
    const int excl = woff + incl - tsum;
    if (base + 0 < N) row_ptr[base + 0] = excl;
    if (base + 1 < N) row_ptr[base + 1] = excl + v.x;
    if (base + 2 < N) row_ptr[base + 2] = excl + v.x + v.y;
    if (base + 3 < N) row_ptr[base + 3] = excl + v.x + v.y + v.z;
    if (tid == 255) blk_sums[blockIdx.x] = woff + incl;
}

// --- scan phase B: one wave scans block totals (nblk <= 64) ----------------
__global__ void k_scan_top(int* __restrict__ blk_sums, int* __restrict__ row_ptr,
                           int nblk, int N) {
    const int lane = threadIdx.x;
    int v = (lane < nblk) ? blk_sums[lane] : 0;
    int incl = v;
    #pragma unroll
    for (int off = 1; off < 64; off <<= 1) {
        int t = __shfl_up(incl, off);
        if (lane >= off) incl += t;
    }
    if (lane < nblk) blk_sums[lane] = incl - v;
    if (lane == 63) row_ptr[N] = incl;
}

// --- scan phase C fused with dis = rsqrt(deg) ------------------------------
__global__ void k_fix_dis(int* __restrict__ row_ptr, const int* __restrict__ blk_sums,
                          const float* __restrict__ deg, float* __restrict__ dis, int N) {
    int i = blockIdx.x * blockDim.x + threadIdx.x;
    if (i >= N) return;
    row_ptr[i] += blk_sums[i >> 10];
    float d = deg[i];
    dis[i] = d > 0.f ? rsqrtf(fmaxf(d, 1e-12f)) : 0.f;
}

// --- atomic-free scatter: csr[row_ptr[dst]+pos] = {src, w_bits} ------------
__global__ void k_scatter(const int* __restrict__ src, const int* __restrict__ dst,
                          const float* __restrict__ ew, const float* __restrict__ dis,
                          const int* __restrict__ row_ptr, const int* __restrict__ pos,
                          int2* __restrict__ csr, int E) {
    int e = blockIdx.x * blockDim.x + threadIdx.x;
    if (e >= E) return;
    int s = src[e], d = dst[e];
    float wv = -dis[s] * ew[e] * dis[d];
    csr[row_ptr[d] + pos[e]] = make_int2(s, __float_as_int(wv));
}

// ---------------- feature concat -> bf16 -----------------------------------

__global__ void k_concat_bf16(const float* __restrict__ x, const float* __restrict__ pe,
                              uint32* __restrict__ h, int N) {
    int i = blockIdx.x * blockDim.x + threadIdx.x;   // bf16-pair index
    if (i >= N * 64) return;
    int node = i >> 6, p = i & 63;
    float f0, f1;
    if (p < 56) { f0 = x[node * 112 + p * 2]; f1 = x[node * 112 + p * 2 + 1]; }
    else { int q = (p - 56) * 2; f0 = pe[node * 16 + q]; f1 = pe[node * 16 + q + 1]; }
    h[i] = (uint32)f2bf(f0) | ((uint32)f2bf(f1) << 16);
}

// ---------------- weight packing (fused, recurrence-transformed) -----------
// Layer transform (exact fp32): out = h(W0-W2) + Ph(W1-3W3) + P^2h(2W2) + P^3h(4W3)
// B-frag (16x16x32): lane l holds B[k=(l>>4)*8+j][col], j=0..7.

__device__ inline float wtrans(const float* __restrict__ W, int kb, size_t o) {
    switch (kb) {
        case 0:  return W[o] - W[o + 32768];
        case 1:  return W[o + 16384] - 3.f * W[o + 49152];
        case 2:  return 2.f * W[o + 32768];
        default: return 4.f * W[o + 49152];
    }
}

__global__ void k_pack_all(const float* __restrict__ W1, const float* __restrict__ W2,
                           const float* __restrict__ Wm, const float* __restrict__ Wl,
                           ushort16* __restrict__ W1p, ushort16* __restrict__ W2p,
                           ushort16* __restrict__ WHp) {
    int t = blockIdx.x * blockDim.x + threadIdx.x;
    uint32 v[8];
    if (t < 16384) {   // layer packs: 2 x 16 ks x 8 c x 64 lanes
        const float* W = (t < 8192) ? W1 : W2;
        ushort16* Wp = (t < 8192) ? W1p : W2p;
        int tt = t & 8191;
        int l = tt & 63, c = (tt >> 6) & 7, ks = tt >> 9;
        int kb = ks >> 2;
        int r0 = (ks & 3) * 32 + (l >> 4) * 8;
        int col = c * 16 + (l & 15);
        #pragma unroll
        for (int j = 0; j < 8; ++j)
            v[j] = f2bf(wtrans(W, kb, (size_t)(r0 + j) * 128 + col));
        uint4 o;
        o.x = v[0] | (v[1] << 16); o.y = v[2] | (v[3] << 16);
        o.z = v[4] | (v[5] << 16); o.w = v[6] | (v[7] << 16);
        *(uint4*)(Wp + (size_t)tt * 8) = o;
    } else if (t < 16384 + 2048) {   // head pack: cols = [mu | lv]
        int tt = t - 16384;
        int l = tt & 63, c = (tt >> 6) & 7, ks = tt >> 9;
        int k0 = ks * 32 + (l >> 4) * 8;
        int cc = c * 16 + (l & 15);
        const float* Ws = (cc < 64) ? Wm : Wl;
        int col = cc & 63;
        #pragma unroll
        for (int j = 0; j < 8; ++j) v[j] = f2bf(Ws[(size_t)(k0 + j) * 64 + col]);
        uint4 o;
        o.x = v[0] | (v[1] << 16); o.y = v[2] | (v[3] << 16);
        o.z = v[4] | (v[5] << 16); o.w = v[6] | (v[7] << 16);
        *(uint4*)(WHp + (size_t)tt * 8) = o;
    }
}

// ---------------- pure gather prop: out = P * tin  (bf16 features) ---------
// wave per node; lane covers 2 feats; 8 gathers in flight, zero-padded tail.

__global__ void k_prop(const uint32* __restrict__ tin, const int2* __restrict__ csr,
                       const int* __restrict__ row_ptr, uint32* __restrict__ out, int N) {
    int wid = (blockIdx.x * blockDim.x + threadIdx.x) >> 6;
    int lane = threadIdx.x & 63;
    if (wid >= N) return;
    int beg = row_ptr[wid], end = row_ptr[wid + 1];
    float ax = 0.f, ay = 0.f;
    for (int base = beg; base < end; base += 64) {
        int m = end - base; if (m > 64) m = 64;
        int2 ev = (lane < m) ? csr[base + lane] : make_int2(0, 0);
        for (int j = 0; j < m; j += 8) {
            #pragma unroll
            for (int u = 0; u < 8; ++u) {       // j+u <= 63 always; pad lanes w=0
                int s = __shfl(ev.x, j + u);
                float w = __uint_as_float(__shfl(ev.y, j + u));
                uint32 v = tin[(size_t)s * 64 + lane];
                ax = fmaf(w, bflo(v), ax); ay = fmaf(w, bfhi(v), ay);
            }
        }
    }
    out[(size_t)wid * 64 + lane] = (uint32)f2bf(ax) | ((uint32)f2bf(ay) << 16);
}

// ---------------- MFMA GEMM: C[N,128] = relu(sum_t T_t @ W_t + b), K=512 ---

template<bool RELU>
__launch_bounds__(256)
__global__ void k_mfma_gemm512(const ushort16* __restrict__ t0, const ushort16* __restrict__ t1,
                               const ushort16* __restrict__ t2, const ushort16* __restrict__ t3,
                               const ushort16* __restrict__ Wp, const float* __restrict__ bias,
                               ushort16* __restrict__ C, int N) {
    const int lane = threadIdx.x & 63;
    const int wave = threadIdx.x >> 6;
    const int brow = blockIdx.x * 128 + wave * 32;
    int r0 = brow + (lane & 15);
    int r1 = r0 + 16;
    if (r0 >= N) r0 = N - 1;
    if (r1 >= N) r1 = N - 1;
    const int kg8 = (lane >> 4) * 8;
    f32x4 acc[2][8] = {};
    #pragma unroll
    for (int t = 0; t < 4; ++t) {
        const ushort16* __restrict__ A = (t == 0) ? t0 : (t == 1) ? t1 : (t == 2) ? t2 : t3;
        const ushort16* a0p = A + (size_t)r0 * 128 + kg8;
        const ushort16* a1p = A + (size_t)r1 * 128 + kg8;
        #pragma unroll
        for (int ks2 = 0; ks2 < 4; ++ks2) {
            bf16x8 a0 = *(const bf16x8*)(a0p + ks2 * 32);
            bf16x8 a1 = *(const bf16x8*)(a1p + ks2 * 32);
            const ushort16* bp = Wp + (size_t)((t * 4 + ks2) * 8 * 64 + lane) * 8;
            #pragma unroll
            for (int c = 0; c < 8; ++c) {
                bf16x8 b = *(const bf16x8*)(bp + c * 512);
                acc[0][c] = __builtin_amdgcn_mfma_f32_16x16x32_bf16(a0, b, acc[0][c], 0, 0, 0);
                acc[1][c] = __builtin_amdgcn_mfma_f32_16x16x32_bf16(a1, b, acc[1][c], 0, 0, 0);
            }
        }
    }
    const int col0 = lane & 15;
    const int rj = (lane >> 4) * 4;
    #pragma unroll
    for (int m = 0; m < 2; ++m) {
        #pragma unroll
        for (int c = 0; c < 8; ++c) {
            float bv = bias[c * 16 + col0];
            #pragma unroll
            for (int j = 0; j < 4; ++j) {
                int row = brow + m * 16 + rj + j;
                if (row < N) {
                    float v = acc[m][c][j] + bv;
                    if (RELU) v = fmaxf(v, 0.f);
                    C[(size_t)row * 128 + c * 16 + col0] = f2bf(v);
                }
            }
        }
    }
}

// ---------------- fused heads via MFMA: [N,128]@[128,128], cols=[mu|lv] ----

__launch_bounds__(256)
__global__ void k_mfma_head(const ushort16* __restrict__ A, const ushort16* __restrict__ Wp,
                            const float* __restrict__ bm, const float* __restrict__ bl,
                            float* __restrict__ out, int N) {
    const int lane = threadIdx.x & 63;
    const int wave = threadIdx.x >> 6;
    const int brow = blockIdx.x * 128 + wave * 32;
    int r0 = brow + (lane & 15);
    int r1 = r0 + 16;
    if (r0 >= N) r0 = N - 1;
    if (r1 >= N) r1 = N - 1;
    const int kg8 = (lane >> 4) * 8;
    f32x4 acc[2][8] = {};
    const ushort16* a0p = A + (size_t)r0 * 128 + kg8;
    const ushort16* a1p = A + (size_t)r1 * 128 + kg8;
    #pragma unroll
    for (int ks = 0; ks < 4; ++ks) {
        bf16x8 a0 = *(const bf16x8*)(a0p + ks * 32);
        bf16x8 a1 = *(const bf16x8*)(a1p + ks * 32);
        const ushort16* bp = Wp + (size_t)(ks * 8 * 64 + lane) * 8;
        #pragma unroll
        for (int c = 0; c < 8; ++c) {
            bf16x8 b = *(const bf16x8*)(bp + c * 512);
            acc[0][c] = __builtin_amdgcn_mfma_f32_16x16x32_bf16(a0, b, acc[0][c], 0, 0, 0);
            acc[1][c] = __builtin_amdgcn_mfma_f32_16x16x32_bf16(a1, b, acc[1][c], 0, 0, 0);
        }
    }
    const int col0 = lane & 15;
    const int rj = (lane >> 4) * 4;
    #pragma unroll
    for (int m = 0; m < 2; ++m) {
        #pragma unroll
        for (int c = 0; c < 8; ++c) {
            int gcol = (c & 3) * 16 + col0;
            float bv = (c < 4) ? bm[gcol] : bl[gcol];
            size_t hoff = (c < 4) ? 0 : (size_t)N * 64;
            #pragma unroll
            for (int j = 0; j < 4; ++j) {
                int row = brow + m * 16 + rj + j;
                if (row < N)
                    out[hoff + (size_t)row * 64 + gcol] = acc[m][c][j] + bv;
            }
        }
    }
}

// ---------------------------------------------------------------------------

extern "C" void kernel_launch(void* const* d_in, const int* in_sizes, int n_in,
                              void* d_out, int out_size, void* d_ws, size_t ws_size,
                              hipStream_t stream) {
    const float* x   = (const float*)d_in[0];
    const int*   ei  = (const int*)d_in[1];
    const float* pe  = (const float*)d_in[2];
    const float* ew  = (const float*)d_in[3];
    const float* W1  = (const float*)d_in[4];
    const float* b1  = (const float*)d_in[5];
    const float* W2  = (const float*)d_in[6];
    const float* b2  = (const float*)d_in[7];
    const float* Wmu = (const float*)d_in[8];
    const float* bmu = (const float*)d_in[9];
    const float* Wlv = (const float*)d_in[10];
    const float* blv = (const float*)d_in[11];

    const int N = in_sizes[0] / 112;
    const int E = in_sizes[1] / 2;
    const int* src = ei;
    const int* dst = ei + E;

    char* ws = (char*)d_ws;
    size_t off = 0;
    auto alloc = [&](size_t bytes) -> char* {
        char* p = ws + off;
        off = (off + bytes + 255) & ~(size_t)255;
        return p;
    };
    float* deg     = (float*)alloc((size_t)N * 4);
    int*   cnt     = (int*)  alloc((size_t)N * 4);
    float* dis     = (float*)alloc((size_t)N * 4);
    int*   row_ptr = (int*)  alloc((size_t)(N + 1) * 4);
    int*   blk_sums= (int*)  alloc((size_t)256 * 4);
    int*   pos     = (int*)  alloc((size_t)E * 4);
    int2*  csr     = (int2*) alloc((size_t)E * 8);
    ushort16* W1p  = (ushort16*)alloc((size_t)512 * 128 * 2);
    ushort16* W2p  = (ushort16*)alloc((size_t)512 * 128 * 2);
    ushort16* WHp  = (ushort16*)alloc((size_t)128 * 128 * 2);
    ushort16* B0 = (ushort16*)alloc((size_t)N * 128 * 2);
    ushort16* B1 = (ushort16*)alloc((size_t)N * 128 * 2);
    ushort16* B2 = (ushort16*)alloc((size_t)N * 128 * 2);
    ushort16* B3 = (ushort16*)alloc((size_t)N * 128 * 2);
    ushort16* B4 = (ushort16*)alloc((size_t)N * 128 * 2);

    hipMemsetAsync(deg, 0, (size_t)N * 4, stream);
    hipMemsetAsync(cnt, 0, (size_t)N * 4, stream);

    const int eb = (E + 255) / 256;
    const int nb = (N + 255) / 256;
    const int pb = (N + 3) / 4;          // wave-per-node, 4 waves/block
    const int gb = (N + 127) / 128;      // 128 rows/block MFMA tiles
    const int nblk = (N + 1023) / 1024;  // 49 for N=50000 (<= 64 required)

    k_deg_cnt<<<eb, 256, 0, stream>>>(src, dst, ew, deg, cnt, pos, E);
    k_scan_blk<<<nblk, 256, 0, stream>>>(cnt, row_ptr, blk_sums, N);
    k_scan_top<<<1, 64, 0, stream>>>(blk_sums, row_ptr, nblk, N);
    k_fix_dis<<<nb, 256, 0, stream>>>(row_ptr, blk_sums, deg, dis, N);
    k_scatter<<<eb, 256, 0, stream>>>(src, dst, ew, dis, row_ptr, pos, csr, E);
    k_concat_bf16<<<(N * 64 + 255) / 256, 256, 0, stream>>>(x, pe, (uint32*)B0, N);
    k_pack_all<<<(16384 + 2048 + 255) / 256, 256, 0, stream>>>(W1, W2, Wmu, Wlv, W1p, W2p, WHp);

    // layer 1: Y1=P*B0, Y2=P*Y1, Y3=P*Y2 -> gemm(transformed W1) -> relu -> B4
    k_prop<<<pb, 256, 0, stream>>>((uint32*)B0, csr, row_ptr, (uint32*)B1, N);
    k_prop<<<pb, 256, 0, stream>>>((uint32*)B1, csr, row_ptr, (uint32*)B2, N);
    k_prop<<<pb, 256, 0, stream>>>((uint32*)B2, csr, row_ptr, (uint32*)B3, N);
    k_mfma_gemm512<true><<<gb, 256, 0, stream>>>(B0, B1, B2, B3, W1p, b1, B4, N);

    // layer 2: Y1=P*B4, Y2, Y3 -> gemm(transformed W2) -> relu -> B3
    k_prop<<<pb, 256, 0, stream>>>((uint32*)B4, csr, row_ptr, (uint32*)B0, N);
    k_prop<<<pb, 256, 0, stream>>>((uint32*)B0, csr, row_ptr, (uint32*)B1, N);
    k_prop<<<pb, 256, 0, stream>>>((uint32*)B1, csr, row_ptr, (uint32*)B2, N);
    k_mfma_gemm512<true><<<gb, 256, 0, stream>>>(B4, B0, B1, B2, W2p, b2, B3, N);

    // heads -> d_out = [mu ; logvar] fp32
    k_mfma_head<<<gb, 256, 0, stream>>>(B3, WHp, bmu, blv, (float*)d_out, N);
}